// Round 4
// baseline (78.864 us; speedup 1.0000x reference)
//
#include <hip/hip_runtime.h>
#include <stdint.h>

#define BS   16384
#define XRW  768
#define HD   256
#define DIN  1280
#define N4   1024
#define NKT  40   // 1280 / 32 K-tiles (BK=32)

typedef __attribute__((ext_vector_type(4))) float f32x4;
typedef __attribute__((ext_vector_type(8))) short s16x8;

__device__ __forceinline__ unsigned short f2bf(float f) {
  uint32_t u = __builtin_bit_cast(uint32_t, f);
  u += 0x7FFFu + ((u >> 16) & 1u);   // RNE
  return (unsigned short)(u >> 16);
}
__device__ __forceinline__ float sigmoidf_(float x) {
  return 1.0f / (1.0f + __expf(-x));
}
__device__ __forceinline__ float tanhf_(float x) {
  return 1.0f - 2.0f / (__expf(2.0f * x) + 1.0f);
}
__device__ __forceinline__ void gload16(const void* g, void* l) {
  __builtin_amdgcn_global_load_lds((const __attribute__((address_space(1))) void*)g,
                                   (__attribute__((address_space(3))) void*)l, 16, 0, 0);
}

// ---- Wt[n'][k] bf16 row-major, n' = h*4 + gate; b4[n'].
__global__ void conv_w_kernel(const float* __restrict__ Wi, const float* __restrict__ bi,
                              const float* __restrict__ Wf, const float* __restrict__ bfv,
                              const float* __restrict__ Wo, const float* __restrict__ bo,
                              const float* __restrict__ Ws, const float* __restrict__ bsv,
                              unsigned short* __restrict__ Wt, float* __restrict__ b4) {
  const int np = blockIdx.x;
  const int h = np >> 2, g = np & 3;
  const float* W  = (g == 0) ? Wi : (g == 1) ? Wf : (g == 2) ? Wo : Ws;
  const float* bb = (g == 0) ? bi : (g == 1) ? bfv : (g == 2) ? bo : bsv;
  if (threadIdx.x == 0) b4[np] = bb[h];
  for (int k = threadIdx.x; k < DIN; k += 256)
    Wt[np * DIN + k] = f2bf(W[k * HD + h]);
}

// ---- Abf[m][k] bf16 row-major = concat(x, pt, pl). Memory-bound (BW roofline).
__global__ __launch_bounds__(256) void conv_a_kernel(const float* __restrict__ X,
                                                     const float* __restrict__ PT,
                                                     const float* __restrict__ PL,
                                                     unsigned short* __restrict__ Abf) {
  const int idx = blockIdx.x * 256 + threadIdx.x;   // [0, 16384*160)
  const int m = idx / 160;
  const int c = idx - m * 160;
  const int k = c << 3;
  const float* src;
  if (k < XRW)           src = X  + (size_t)m * XRW + k;
  else if (k < XRW + HD) src = PT + (size_t)m * HD + (k - XRW);
  else                   src = PL + (size_t)m * HD + (k - XRW - HD);
  f32x4 a = *(const f32x4*)src;
  f32x4 b = *(const f32x4*)(src + 4);
  s16x8 o;
  o[0] = (short)f2bf(a.x); o[1] = (short)f2bf(a.y);
  o[2] = (short)f2bf(a.z); o[3] = (short)f2bf(a.w);
  o[4] = (short)f2bf(b.x); o[5] = (short)f2bf(b.y);
  o[6] = (short)f2bf(b.z); o[7] = (short)f2bf(b.w);
  *(s16x8*)(Abf + (size_t)idx * 8) = o;
}

// ---- 256x256 tile, BK=32, 8 waves (2M x 4N), 4 single-K-tile LDS buffers,
// 2 fine phases per K-tile, constant vmcnt(8) (3-tile prefetch depth).
// Swizzle: phys_col = logical_col ^ (((row>>1)&3)<<4) within 64B rows,
// applied on the pre-swizzled global source AND the ds_read address.
__global__ __launch_bounds__(512, 2)
void lstm_gemm_kernel(const unsigned short* __restrict__ Abf,
                      const unsigned short* __restrict__ Wt,
                      const float* __restrict__ b4,
                      const float* __restrict__ OLD,
                      float* __restrict__ out) {
  __shared__ unsigned char smem[131072];   // A: 4 bufs x 16KB @0; B: 4 x 16KB @64K
  const int tid  = threadIdx.x;
  const int wid  = tid >> 6;
  const int lane = tid & 63;

  // T1: each XCD owns 8 contiguous M-panels x all 4 N-tiles (grid=256, 1 blk/CU)
  const int H = blockIdx.x;
  const int xcd = H & 7, slot = H >> 3;          // slot in [0,32)
  const int mt = xcd * 8 + (slot >> 2);          // [0,64)
  const int nt = slot & 3;                       // [0,4)
  const int wr = wid >> 2, wc = wid & 3;

  // ---- staging addressing: per K-tile per operand, 2 gloads of 8KB (128 rows).
  // LDS phys (row = c*128 + t>>2, col = (t&3)*16); source col pre-swizzled.
  const int scol = ((tid & 3) ^ ((tid >> 3) & 3)) << 4;
  const char* gA0 = (const char*)Abf + (size_t)(mt * 256 + (tid >> 2)) * (DIN * 2) + scol;
  const char* gB0 = (const char*)Wt  + (size_t)(nt * 256 + (tid >> 2)) * (DIN * 2) + scol;

#define STAGE_A(s, sb) do {                                                   \
    const char* g_ = gA0 + (size_t)(s) * 64;                                  \
    gload16(g_,          &smem[(sb) * 16384 + (tid << 4)]);                   \
    gload16(g_ + 327680, &smem[(sb) * 16384 + 8192 + (tid << 4)]);            \
  } while (0)
#define STAGE_B(s, sb) do {                                                   \
    const char* g_ = gB0 + (size_t)(s) * 64;                                  \
    gload16(g_,          &smem[65536 + (sb) * 16384 + (tid << 4)]);           \
    gload16(g_ + 327680, &smem[65536 + (sb) * 16384 + 8192 + (tid << 4)]);    \
  } while (0)

  // ---- frag read addressing (per-lane invariant)
  const int rx   = lane & 15;
  const int colq = ((lane >> 4) << 4) ^ ((((lane & 15) >> 1) & 3) << 4);
  const int aBase = (wr * 128 + rx) * 64 + colq;            // + buf*16384 + mf*1024
  const int bBase = 65536 + (wc * 64 + rx) * 64 + colq;     // + buf*16384 + nf*1024

  f32x4 acc[8][4];
  #pragma unroll
  for (int i = 0; i < 8; ++i)
    #pragma unroll
    for (int j = 0; j < 4; ++j) {
      f32x4 z = {0.0f, 0.0f, 0.0f, 0.0f};
      acc[i][j] = z;
    }

#define VMW(N) asm volatile("s_waitcnt vmcnt(" #N ")" ::: "memory")
#define LGKM0() do { asm volatile("s_waitcnt lgkmcnt(0)" ::: "memory");       \
                     __builtin_amdgcn_sched_barrier(0); } while (0)

  // Two phases per K-tile; buffer index is STATIC (tile j lives in buf j&3).
#define DO_TILE(B, SA_, SB_, VM_) do {                                        \
    s16x8 aq[4], bq[4], aq2[4];                                               \
    _Pragma("unroll")                                                         \
    for (int mf = 0; mf < 4; ++mf)                                            \
      aq[mf] = *(const s16x8*)(&smem[(B) * 16384 + aBase + mf * 1024]);       \
    _Pragma("unroll")                                                         \
    for (int nf = 0; nf < 4; ++nf)                                            \
      bq[nf] = *(const s16x8*)(&smem[(B) * 16384 + bBase + nf * 1024]);       \
    SA_;                                                                      \
    __builtin_amdgcn_s_barrier();                                             \
    LGKM0();                                                                  \
    __builtin_amdgcn_s_setprio(1);                                            \
    _Pragma("unroll")                                                         \
    for (int mf = 0; mf < 4; ++mf)                                            \
      _Pragma("unroll")                                                       \
      for (int nf = 0; nf < 4; ++nf)                                          \
        acc[mf][nf] = __builtin_amdgcn_mfma_f32_16x16x32_bf16(aq[mf], bq[nf], \
                                                      acc[mf][nf], 0, 0, 0);  \
    __builtin_amdgcn_s_setprio(0);                                            \
    __builtin_amdgcn_s_barrier();                                             \
    _Pragma("unroll")                                                         \
    for (int mf = 0; mf < 4; ++mf)                                            \
      aq2[mf] = *(const s16x8*)(&smem[(B) * 16384 + aBase + 4096 + mf * 1024]);\
    SB_;                                                                      \
    __builtin_amdgcn_s_barrier();                                             \
    LGKM0();                                                                  \
    __builtin_amdgcn_s_setprio(1);                                            \
    _Pragma("unroll")                                                         \
    for (int mf = 0; mf < 4; ++mf)                                            \
      _Pragma("unroll")                                                       \
      for (int nf = 0; nf < 4; ++nf)                                          \
        acc[4 + mf][nf] = __builtin_amdgcn_mfma_f32_16x16x32_bf16(aq2[mf],    \
                                          bq[nf], acc[4 + mf][nf], 0, 0, 0);  \
    __builtin_amdgcn_s_setprio(0);                                            \
    VM_;                                                                      \
    __builtin_amdgcn_s_barrier();                                             \
  } while (0)

  // prologue: stage tiles 0,1,2 (12 loads); wait tile 0 (8 newer outstanding)
  STAGE_A(0, 0); STAGE_B(0, 0);
  STAGE_A(1, 1); STAGE_B(1, 1);
  STAGE_A(2, 2); STAGE_B(2, 2);
  VMW(8);
  __builtin_amdgcn_s_barrier();

  for (int j = 0; j < 36; j += 4) {
    DO_TILE(0, STAGE_A(j + 3, 3), STAGE_B(j + 3, 3), VMW(8));
    DO_TILE(1, STAGE_A(j + 4, 0), STAGE_B(j + 4, 0), VMW(8));
    DO_TILE(2, STAGE_A(j + 5, 1), STAGE_B(j + 5, 1), VMW(8));
    DO_TILE(3, STAGE_A(j + 6, 2), STAGE_B(j + 6, 2), VMW(8));
  }
  DO_TILE(0, STAGE_A(39, 3), STAGE_B(39, 3), VMW(8));   // tile 36
  DO_TILE(1, , , VMW(4));                               // tile 37
  DO_TILE(2, , , VMW(0));                               // tile 38
  DO_TILE(3, , , );                                     // tile 39

  // ---- fused epilogue: acc -> LDS (8KB/wave) -> gates -> new_hidden,new_state
  __syncthreads();
  float* creg = (float*)smem + wid * 2048;   // [32][64] f32 per wave
  const int mbase = mt * 256 + wr * 128;
  const int hbase = nt * 64 + wc * 16;
  const int bcol  = nt * 256 + wc * 64;
  #pragma unroll
  for (int p = 0; p < 4; ++p) {
    #pragma unroll
    for (int mf2 = 0; mf2 < 2; ++mf2) {
      #pragma unroll
      for (int nf = 0; nf < 4; ++nf) {
        const int lrow = mf2 * 16 + (lane >> 4) * 4;   // C/D: row=(lane>>4)*4+r
        const int lcol = nf * 16 + (lane & 15);        //      col=lane&15
        #pragma unroll
        for (int r = 0; r < 4; ++r)
          creg[(lrow + r) * 64 + lcol] = acc[p * 2 + mf2][nf][r];
      }
    }
    #pragma unroll
    for (int j = 0; j < 8; ++j) {
      const int idx = lane + j * 64;
      const int row = idx >> 4;
      const int hc  = idx & 15;
      f32x4 g4 = *(f32x4*)(creg + row * 64 + hc * 4);
      f32x4 bb = *(const f32x4*)(b4 + bcol + hc * 4);
      const int m  = mbase + p * 32 + row;
      const int hg = hbase + hc;
      const float ig = sigmoidf_(g4.x + bb.x);
      const float fg = sigmoidf_(g4.y + bb.y);
      const float og = sigmoidf_(g4.z + bb.z);
      const float cg = tanhf_(g4.w + bb.w);
      const float ns = fg * OLD[m * HD + hg] + ig * cg;
      const float nh = og * tanhf_(ns);
      out[m * HD + hg] = nh;
      out[BS * HD + m * HD + hg] = ns;
    }
  }
#undef STAGE_A
#undef STAGE_B
#undef VMW
#undef LGKM0
#undef DO_TILE
}

extern "C" void kernel_launch(void* const* d_in, const int* in_sizes, int n_in,
                              void* d_out, int out_size, void* d_ws, size_t ws_size,
                              hipStream_t stream) {
  const float* X   = (const float*)d_in[0];
  const float* PT  = (const float*)d_in[1];
  const float* PL  = (const float*)d_in[2];
  const float* OLD = (const float*)d_in[3];
  const float* Wi  = (const float*)d_in[4];
  const float* bi  = (const float*)d_in[5];
  const float* Wf  = (const float*)d_in[6];
  const float* bfv = (const float*)d_in[7];
  const float* Wo  = (const float*)d_in[8];
  const float* bo  = (const float*)d_in[9];
  const float* Ws  = (const float*)d_in[10];
  const float* bsv = (const float*)d_in[11];
  float* out = (float*)d_out;

  unsigned short* Wt  = (unsigned short*)d_ws;                              // 2.62 MB
  float*          b4  = (float*)((char*)d_ws + (size_t)N4 * DIN * 2);       // 4 KB
  unsigned short* Abf = (unsigned short*)((char*)d_ws + (size_t)N4 * DIN * 2 + 4096);  // 41.9 MB

  conv_w_kernel<<<N4, 256, 0, stream>>>(Wi, bi, Wf, bfv, Wo, bo, Ws, bsv, Wt, b4);
  conv_a_kernel<<<(BS * (DIN / 8)) / 256, 256, 0, stream>>>(X, PT, PL, Abf);
  lstm_gemm_kernel<<<256, 512, 0, stream>>>(Abf, Wt, b4, OLD, out);
}

// Round 5
// 64.105 us; speedup vs baseline: 1.2302x; 1.2302x over previous
//
#include <hip/hip_runtime.h>
#include <stdint.h>

#define BS   16384
#define XRW  768
#define HD   256
#define DIN  1280
#define N4   1024
#define NKT  20   // 1280 / 64 K-tiles

typedef __attribute__((ext_vector_type(4))) float f32x4;
typedef __attribute__((ext_vector_type(8))) short s16x8;
typedef __attribute__((ext_vector_type(4))) unsigned int u32x4;

__device__ __forceinline__ unsigned short f2bf(float f) {
  uint32_t u = __builtin_bit_cast(uint32_t, f);
  u += 0x7FFFu + ((u >> 16) & 1u);   // RNE
  return (unsigned short)(u >> 16);
}
__device__ __forceinline__ uint32_t cvtpk(float a, float b) {
  uint32_t d;
  asm("v_cvt_pk_bf16_f32 %0, %1, %2" : "=v"(d) : "v"(a), "v"(b));
  return d;
}
__device__ __forceinline__ float sigmoidf_(float x) {
  return 1.0f / (1.0f + __expf(-x));
}
__device__ __forceinline__ float tanhf_(float x) {
  return 1.0f - 2.0f / (__expf(2.0f * x) + 1.0f);
}
__device__ __forceinline__ void gload16(const void* g, void* l) {
  __builtin_amdgcn_global_load_lds((const __attribute__((address_space(1))) void*)g,
                                   (__attribute__((address_space(3))) void*)l, 16, 0, 0);
}

// ---- Wt[n'][k] bf16 row-major, n' = h*4 + gate; b4[n'].
__global__ void conv_w_kernel(const float* __restrict__ Wi, const float* __restrict__ bi,
                              const float* __restrict__ Wf, const float* __restrict__ bfv,
                              const float* __restrict__ Wo, const float* __restrict__ bo,
                              const float* __restrict__ Ws, const float* __restrict__ bsv,
                              unsigned short* __restrict__ Wt, float* __restrict__ b4) {
  const int np = blockIdx.x;
  const int h = np >> 2, g = np & 3;
  const float* W  = (g == 0) ? Wi : (g == 1) ? Wf : (g == 2) ? Wo : Ws;
  const float* bb = (g == 0) ? bi : (g == 1) ? bfv : (g == 2) ? bo : bsv;
  if (threadIdx.x == 0) b4[np] = bb[h];
  for (int k = threadIdx.x; k < DIN; k += 256)
    Wt[np * DIN + k] = f2bf(W[k * HD + h]);
}

// ---- 256x256 tile, BK=64, 8 waves (2M x 4N), 2-buffer LDS.
// A = concat(x,pt,pl) loaded f32 -> regs (issue-early) -> cvt_pk bf16 ->
// swizzled ds_write (conv_a pass fused away). B via global_load_lds with
// pre-swizzled source. Fused gate epilogue.
__global__ __launch_bounds__(512, 2)
void lstm_gemm_kernel(const float* __restrict__ X,
                      const float* __restrict__ PT,
                      const float* __restrict__ PL,
                      const unsigned short* __restrict__ Wt,
                      const float* __restrict__ b4,
                      const float* __restrict__ OLD,
                      float* __restrict__ out) {
  __shared__ unsigned char smem[131072];  // A: 2x32KB @0; B: 2x32KB @64K
  const int tid  = threadIdx.x;
  const int wid  = tid >> 6;
  const int lane = tid & 63;

  // T1: XCD owns 8 contiguous M-panels x all 4 N-tiles; nt fastest ->
  // the 4 nt-siblings of an mt are co-resident and share A via L2.
  const int H = blockIdx.x;
  const int xcd = H & 7, slot = H >> 3;          // slot in [0,32)
  const int mt = xcd * 8 + (slot >> 2);          // [0,64)
  const int nt = slot & 3;                       // [0,4)
  const int wr = wid >> 2, wc = wid & 3;

  // ---- B staging (gload_lds, linear LDS dest, pre-swizzled source col)
  const int r8   = lane >> 3;
  const int scol = ((lane & 7) ^ r8) << 4;
  const char* gB = (const char*)Wt + (size_t)(nt * 256 + wid * 8 + r8) * (DIN * 2) + scol;

#define STAGE_B(t1, o) do {                                                   \
    const int kb_ = (t1) * 128;                                               \
    _Pragma("unroll")                                                         \
    for (int c_ = 0; c_ < 4; ++c_)                                            \
      gload16(gB + (size_t)c_ * (64 * DIN * 2) + kb_,                         \
              &smem[65536 + (o) * 32768 + c_ * 8192 + wid * 1024]);           \
  } while (0)

  // ---- A reg staging: per thread 32 f32 = 4 chunks (row, 8 floats);
  // chunk rows = arow + {0,64,128,192}; halves H0={0,64}, H1={128,192}.
  const int arow  = tid >> 3;
  const int a7    = tid & 7;
  const int awcol = ((a7 ^ (arow & 7)) << 4);   // phys col = logical ^ (row&7)<<4

#define ALOAD(t1, h) do {                                                     \
    const float* asrc_; int astr_, aoff_;                                     \
    if ((t1) < 12)      { asrc_ = X;  astr_ = XRW; aoff_ = (t1) * 64; }       \
    else if ((t1) < 16) { asrc_ = PT; astr_ = HD;  aoff_ = ((t1) - 12) * 64; }\
    else                { asrc_ = PL; astr_ = HD;  aoff_ = ((t1) - 16) * 64; }\
    const float* ga_ = asrc_ + (size_t)(mt * 256 + arow + (h) * 128) * astr_  \
                             + aoff_ + a7 * 8;                                \
    ar0 = *(const f32x4*)(ga_);                                               \
    ar1 = *(const f32x4*)(ga_ + 4);                                           \
    ar2 = *(const f32x4*)(ga_ + (size_t)64 * astr_);                          \
    ar3 = *(const f32x4*)(ga_ + (size_t)64 * astr_ + 4);                      \
  } while (0)

#define AWRITE(o, h) do {                                                     \
    u32x4 w0_, w1_;                                                           \
    w0_.x = cvtpk(ar0.x, ar0.y); w0_.y = cvtpk(ar0.z, ar0.w);                 \
    w0_.z = cvtpk(ar1.x, ar1.y); w0_.w = cvtpk(ar1.z, ar1.w);                 \
    w1_.x = cvtpk(ar2.x, ar2.y); w1_.y = cvtpk(ar2.z, ar2.w);                 \
    w1_.z = cvtpk(ar3.x, ar3.y); w1_.w = cvtpk(ar3.z, ar3.w);                 \
    *(u32x4*)(&smem[(o) * 32768 + ((arow + (h) * 128)      << 7) + awcol]) = w0_; \
    *(u32x4*)(&smem[(o) * 32768 + ((arow + (h) * 128 + 64) << 7) + awcol]) = w1_; \
  } while (0)

  // ---- frag read addressing (row&7 == lane&7 for all frags)
  const int rx   = lane & 15;
  const int axor = (lane & 7) << 4;
  const int col0 = (((lane >> 4) << 4)) ^ axor;        // kh=0
  const int col1 = (64 + ((lane >> 4) << 4)) ^ axor;   // kh=1
  const int aRow = (wr * 128 + rx) * 128;              // + mf*2048
  const int bRow = 65536 + (wc * 64 + rx) * 128;       // + nf*2048

  f32x4 acc[8][4];
  #pragma unroll
  for (int i = 0; i < 8; ++i)
    #pragma unroll
    for (int j = 0; j < 4; ++j) {
      f32x4 z = {0.0f, 0.0f, 0.0f, 0.0f};
      acc[i][j] = z;
    }

#define VMW(N) asm volatile("s_waitcnt vmcnt(" #N ")" ::: "memory")
#define LGKM0() do { asm volatile("s_waitcnt lgkmcnt(0)" ::: "memory");       \
                     __builtin_amdgcn_sched_barrier(0); } while (0)
#define FRAGS(bo_, kh_col) do {                                               \
    _Pragma("unroll")                                                         \
    for (int mf = 0; mf < 8; ++mf)                                            \
      aq[mf] = *(const s16x8*)(&smem[(bo_) + aRow + mf * 2048 + (kh_col)]);   \
    _Pragma("unroll")                                                         \
    for (int nf = 0; nf < 4; ++nf)                                            \
      bq[nf] = *(const s16x8*)(&smem[(bo_) + bRow + nf * 2048 + (kh_col)]);   \
  } while (0)
#define MFMAS() do {                                                          \
    __builtin_amdgcn_s_setprio(1);                                            \
    _Pragma("unroll")                                                         \
    for (int mf = 0; mf < 8; ++mf)                                            \
      _Pragma("unroll")                                                       \
      for (int nf = 0; nf < 4; ++nf)                                          \
        acc[mf][nf] = __builtin_amdgcn_mfma_f32_16x16x32_bf16(aq[mf], bq[nf], \
                                                      acc[mf][nf], 0, 0, 0);  \
    __builtin_amdgcn_s_setprio(0);                                            \
  } while (0)

  // ---- prologue: fill buf0 with tile 0 (A via regs+cvt, B via gload_lds)
  {
    f32x4 ar0, ar1, ar2, ar3;
    ALOAD(0, 0);
    STAGE_B(0, 0);
    VMW(4);        // A H0 regs landed (B may still fly)
    AWRITE(0, 0);
    ALOAD(0, 1);
    VMW(0);        // A H1 + B(0) landed
    AWRITE(0, 1);
    LGKM0();       // my ds_writes done
    __builtin_amdgcn_s_barrier();
  }

  for (int kt = 0; kt < NKT; ++kt) {
    const int c = kt & 1, o = c ^ 1;
    const int bo_ = c << 15;
    const bool pf = (kt + 1) < NKT;
    s16x8 aq[8], bq[4];
    f32x4 ar0, ar1, ar2, ar3;

    if (pf) ALOAD(kt + 1, 0);          // issue-early: A(k+1) H0 -> regs
    FRAGS(bo_, col0);
    if (pf) STAGE_B(kt + 1, o);        // B(k+1) -> LDS buf o (async)
    LGKM0();
    MFMAS();
    VMW(4);                            // A H0 regs landed
    if (pf) { AWRITE(o, 0); ALOAD(kt + 1, 1); }
    FRAGS(bo_, col1);
    LGKM0();
    MFMAS();
    VMW(0);                            // A H1 regs + B(k+1) in LDS
    if (pf) AWRITE(o, 1);
    LGKM0();                           // my ds_writes visible
    __builtin_amdgcn_s_barrier();      // buf o fully published
  }

  // ---- fused epilogue: acc -> LDS (8KB/wave) -> gates -> new_hidden,new_state
  __syncthreads();
  float* creg = (float*)smem + wid * 2048;   // [32][64] f32 per wave
  const int mbase = mt * 256 + wr * 128;
  const int hbase = nt * 64 + wc * 16;
  const int bcol  = nt * 256 + wc * 64;
  #pragma unroll
  for (int p = 0; p < 4; ++p) {
    #pragma unroll
    for (int mf2 = 0; mf2 < 2; ++mf2) {
      #pragma unroll
      for (int nf = 0; nf < 4; ++nf) {
        const int lrow = mf2 * 16 + (lane >> 4) * 4;   // C/D: row=(lane>>4)*4+r
        const int lcol = nf * 16 + (lane & 15);        //      col=lane&15
        #pragma unroll
        for (int r = 0; r < 4; ++r)
          creg[(lrow + r) * 64 + lcol] = acc[p * 2 + mf2][nf][r];
      }
    }
    #pragma unroll
    for (int j = 0; j < 8; ++j) {
      const int idx = lane + j * 64;
      const int row = idx >> 4;
      const int hc  = idx & 15;
      f32x4 g4 = *(f32x4*)(creg + row * 64 + hc * 4);
      f32x4 bb = *(const f32x4*)(b4 + bcol + hc * 4);
      const int m  = mbase + p * 32 + row;
      const int hg = hbase + hc;
      const float ig = sigmoidf_(g4.x + bb.x);
      const float fg = sigmoidf_(g4.y + bb.y);
      const float og = sigmoidf_(g4.z + bb.z);
      const float cg = tanhf_(g4.w + bb.w);
      const float ns = fg * OLD[m * HD + hg] + ig * cg;
      const float nh = og * tanhf_(ns);
      out[m * HD + hg] = nh;
      out[BS * HD + m * HD + hg] = ns;
    }
  }
#undef STAGE_B
#undef ALOAD
#undef AWRITE
#undef VMW
#undef LGKM0
#undef FRAGS
#undef MFMAS
}

extern "C" void kernel_launch(void* const* d_in, const int* in_sizes, int n_in,
                              void* d_out, int out_size, void* d_ws, size_t ws_size,
                              hipStream_t stream) {
  const float* X   = (const float*)d_in[0];
  const float* PT  = (const float*)d_in[1];
  const float* PL  = (const float*)d_in[2];
  const float* OLD = (const float*)d_in[3];
  const float* Wi  = (const float*)d_in[4];
  const float* bi  = (const float*)d_in[5];
  const float* Wf  = (const float*)d_in[6];
  const float* bfv = (const float*)d_in[7];
  const float* Wo  = (const float*)d_in[8];
  const float* bo  = (const float*)d_in[9];
  const float* Ws  = (const float*)d_in[10];
  const float* bsv = (const float*)d_in[11];
  float* out = (float*)d_out;

  unsigned short* Wt = (unsigned short*)d_ws;                         // 2.62 MB
  float*          b4 = (float*)((char*)d_ws + (size_t)N4 * DIN * 2);  // 4 KB

  conv_w_kernel<<<N4, 256, 0, stream>>>(Wi, bi, Wf, bfv, Wo, bo, Ws, bsv, Wt, b4);
  lstm_gemm_kernel<<<256, 512, 0, stream>>>(X, PT, PL, Wt, b4, OLD, out);
}